// Round 12
// baseline (2250.483 us; speedup 1.0000x reference)
//
#include <hip/hip_runtime.h>
#include <hip/hip_bf16.h>

#define BB 32
#define SS 512
#define HH 512
#define VV 32000
#define EE 768
#define NC 3
#define G4 2048
#define MM (BB*SS)
#define SENT 0xFFFFFFFFu

typedef __attribute__((ext_vector_type(8))) short bf16x8;
typedef __attribute__((ext_vector_type(4))) float f32x4;
typedef unsigned int u32;
typedef unsigned short u16;
typedef __attribute__((ext_vector_type(4))) u32 u32x4;
typedef __attribute__((ext_vector_type(2))) u32 u32x2;

#define MFMA(a,b,c) __builtin_amdgcn_mfma_f32_16x16x32_bf16(a,b,c,0,0,0)

static __device__ __forceinline__ u16 f2bf(float f) {
  union { float f; u32 u; } v; v.f = f;
  return (u16)((v.u + 0x7fffu + ((v.u >> 16) & 1u)) >> 16);
}
static __device__ __forceinline__ float bf2f(u16 h) {
  union { u32 u; float f; } v; v.u = ((u32)h) << 16;
  return v.f;
}
static __device__ __forceinline__ float sigm(float x) { return 1.f/(1.f+__expf(-x)); }
static __device__ __forceinline__ float tanh_f(float x) {
  x = fminf(8.f, fmaxf(-8.f, x));
  float t = __expf(2.f*x);
  return (t-1.f)/(t+1.f);
}
static __device__ __forceinline__ bool ok16(u32 v) {
  return ((v & 0xFFFFu) != 0xFFFFu) && ((v >> 16) != 0xFFFFu);
}

// ---------- merged prep: conv + 5 packs, role by blockIdx ----------
static __device__ void conv_body(int blk, const float* __restrict__ src, u16* __restrict__ dst) {
  int i = blk * 256 + threadIdx.x;
  if (i >= VV*EE/8) return;
  const float4* s = ((const float4*)src) + (size_t)i*2;
  float4 a = s[0], b = s[1];
  u32 x = (u32)f2bf(a.x) | ((u32)f2bf(a.y) << 16);
  u32 y = (u32)f2bf(a.z) | ((u32)f2bf(a.w) << 16);
  u32 z = (u32)f2bf(b.x) | ((u32)f2bf(b.y) << 16);
  u32 w = (u32)f2bf(b.z) | ((u32)f2bf(b.w) << 16);
  ((uint4*)dst)[i] = make_uint4(x, y, z, w);
}
static __device__ void pack_body(int blk, const float* __restrict__ src, u16* __restrict__ dst, int K, int N) {
  int tid = blk * 256 + threadIdx.x;
  int nkf = K >> 5;
  int l = tid & 63, fi = tid >> 6;
  int kf = fi % nkf, nf = fi / nkf;
  if (nf >= (N >> 4)) return;
  int col = nf * 16 + (l & 15);
  int k0 = kf * 32 + (l >> 4) * 8;
  u32 o[4];
  #pragma unroll
  for (int j = 0; j < 4; ++j) {
    u16 lo = f2bf(src[(size_t)(k0 + 2*j) * N + col]);
    u16 hi = f2bf(src[(size_t)(k0 + 2*j + 1) * N + col]);
    o[j] = (u32)lo | ((u32)hi << 16);
  }
  *((uint4*)(dst + (size_t)tid * 8)) = make_uint4(o[0], o[1], o[2], o[3]);
}
__global__ __launch_bounds__(256) void k_prep(
    const float* emb, u16* embT,
    const float* fK, u16* Kfp, const float* bK, u16* Kbp,
    const float* fR, u16* Rfp, const float* bR, u16* Rbp,
    const float* w1, u16* w1p)
{
  int b = blockIdx.x;
  if      (b < 12000) conv_body(b, emb, embT);
  else if (b < 12768) pack_body(b-12000, fK, Kfp, EE, G4);
  else if (b < 13536) pack_body(b-12768, bK, Kbp, EE, G4);
  else if (b < 14048) pack_body(b-13536, fR, Rfp, HH, G4);
  else if (b < 14560) pack_body(b-14048, bR, Rbp, HH, G4);
  else                pack_body(b-14560, w1, w1p, 2*HH, HH);
}

// ---------- proj role: zx2 = gather(emb) @ K + bias + K_prior_row ----------
// zx2 layout: u16 index = ((s*32 + b)*128 + colq)*16 + g*4 + c2
// (4 h-cols x 4 gates contiguous per (s,b,colq) -> scan reads 32B/thread).
// Epilogue: LDS transpose tile [128][136 u16], then dwordx2 sc0 sc1 stores.
static __device__ __forceinline__ void proj_role(
    int pid, char* smem,
    const u16* __restrict__ embT, const u16* __restrict__ Kfp, const u16* __restrict__ Kbp,
    const float* __restrict__ fb_, const float* __restrict__ bb_,
    const float* __restrict__ fK_, const float* __restrict__ bK_,
    const int* __restrict__ ids, const int* __restrict__ prior,
    u16* __restrict__ zx2f, u16* __restrict__ zx2b)
{
  int w = threadIdx.x >> 6, l = threadIdx.x & 63;
  int dir = pid >= 112;
  int i0 = dir ? pid - 112 : pid;
  const u16* Bp = dir ? Kbp : Kfp;
  const float* bias = dir ? bb_ : fb_;
  const float* Kp = (dir ? bK_ : fK_) + (size_t)EE * G4;
  u16* zx2 = dir ? zx2b : zx2f;
  u16* lt = (u16*)smem;                 // [128][136] u16 = 34816B
  for (int i = i0; i < 2048; i += 112) {
    int mtseq = i >> 4, nt = i & 15;
    int mt = dir ? (127 - mtseq) : mtseq;
    int m0 = mt * 128 + w * 32;
    int r0 = m0 + (l & 15);
    int id0 = ids[(r0 & 31) * SS + (r0 >> 5)];
    int id1 = ids[((r0 + 16) & 31) * SS + ((r0 + 16) >> 5)];
    const u16* a0p = embT + (size_t)id0 * EE + (l >> 4) * 8;
    const u16* a1p = embT + (size_t)id1 * EE + (l >> 4) * 8;
    f32x4 acc[2][8];
    #pragma unroll
    for (int a = 0; a < 2; ++a)
      #pragma unroll
      for (int j = 0; j < 8; ++j) acc[a][j] = (f32x4){0.f,0.f,0.f,0.f};
    const u16* bbase = Bp + ((size_t)(nt*8)*24)*512 + (size_t)l*8;
    for (int kf = 0; kf < 24; ++kf) {
      bf16x8 a0 = *(const bf16x8*)(a0p + kf*32);
      bf16x8 a1 = *(const bf16x8*)(a1p + kf*32);
      #pragma unroll
      for (int nf = 0; nf < 8; ++nf) {
        bf16x8 bv = *(const bf16x8*)(bbase + (size_t)(nf*24 + kf)*512);
        acc[0][nf] = MFMA(a0, bv, acc[0][nf]);
        acc[1][nf] = MFMA(a1, bv, acc[1][nf]);
      }
    }
    __syncthreads();   // guard: previous tile's readout done before overwrite
    #pragma unroll
    for (int mi = 0; mi < 2; ++mi) {
      #pragma unroll
      for (int r = 0; r < 4; ++r) {
        int rloc = w*32 + mi*16 + (l >> 4)*4 + r;
        int row = mt*128 + rloc;
        int p = prior[(row & 31) * SS + (row >> 5)];
        const float* kr = Kp + (size_t)p * G4;
        #pragma unroll
        for (int nf = 0; nf < 8; ++nf) {
          int lc = (l & 15) + nf*16;
          int colg = nt*128 + lc;
          lt[rloc*136 + lc] = f2bf(acc[mi][nf][r] + bias[colg] + kr[colg]);
        }
      }
    }
    __syncthreads();   // tile staged
    int g = nt >> 2, cqb = (nt & 3) * 32;
    int cql = threadIdx.x & 31;
    #pragma unroll
    for (int k = 0; k < 8; ++k) {
      int rloc = k*16 + (threadIdx.x >> 5);   // covers 128 rows in 8 iters x 16
      int s = mt*4 + (rloc >> 5);
      int b = rloc & 31;
      u32x2 v0 = *(const u32x2*)(lt + rloc*136 + cql*4);
      u32x2 v1 = *(const u32x2*)(lt + (rloc+8)*136 + cql*4);
      u16* d0 = zx2 + (((size_t)(s*BB + b)*128 + cqb + cql)*16 + g*4);
      int rloc1 = rloc + 8;
      int s1 = mt*4 + (rloc1 >> 5), b1 = rloc1 & 31;
      u16* d1 = zx2 + (((size_t)(s1*BB + b1)*128 + cqb + cql)*16 + g*4);
      asm volatile("global_store_dwordx2 %0, %1, off sc0 sc1" :: "v"(d0), "v"(v0) : "memory");
      asm volatile("global_store_dwordx2 %0, %1, off sc0 sc1" :: "v"(d1), "v"(v1) : "memory");
    }
  }
}

// ---------- fused kernel: wg 0..31 = scan, wg 32..255 = proj workers ----------
__global__ __launch_bounds__(256, 1) void k_fused(
    const u16* __restrict__ embT, const u16* __restrict__ Kfp, const u16* __restrict__ Kbp,
    const float* __restrict__ fb, const float* __restrict__ bb,
    const float* __restrict__ fK, const float* __restrict__ bK,
    const int* __restrict__ ids, const int* __restrict__ prior,
    u16* __restrict__ zx2f, u16* __restrict__ zx2b,
    const u16* __restrict__ Rf, const u16* __restrict__ Rb,
    u16* __restrict__ hf, u16* __restrict__ hb)
{
  __shared__ char smem[50176];
  char* hstage = smem;                                  // 32*1040 = 33280
  float (*zbuf)[32][33] = (float (*)[32][33])(smem + 33280);  // 16896

  int wg = blockIdx.x;
  if (wg >= 32) {
    proj_role(wg - 32, smem, embT, Kfp, Kbp, fb, bb, fK, bK, ids, prior, zx2f, zx2b);
    return;
  }
  int dir = wg >> 4, wgi = wg & 15;
  const u16* zx2 = dir ? zx2b : zx2f;
  const u16* Rp = dir ? Rb : Rf;
  u16* hbuf = dir ? hb : hf;
  int tid = threadIdx.x;
  int g = tid >> 6, l = tid & 63;
  int ncb0 = g*32 + wgi*2;
  bf16x8 rb0[16], rb1[16];
  #pragma unroll
  for (int kf = 0; kf < 16; ++kf) {
    rb0[kf] = *(const bf16x8*)(Rp + (((size_t)ncb0*16 + kf)*64 + l)*8);
    rb1[kf] = *(const bf16x8*)(Rp + (((size_t)(ncb0+1)*16 + kf)*64 + l)*8);
  }

  int eb = tid >> 3;            // batch 0..31
  int q = tid & 7;              // colq within wg
  int colq = wgi*8 + q;         // global colq (4 h-cols)
  const char* sread0 = hstage + (l & 15)*1040 + (l >> 4)*16;
  const char* sread1 = sread0 + 16*1040;
  char* swrite = hstage + (tid >> 3)*1040 + q*16;
  size_t goff = (size_t)(tid >> 3)*1024 + q*16;

  float c0 = 0.f, c1 = 0.f, c2 = 0.f, c3 = 0.f;
  for (int step = 0; step < SS; ++step) {
    int t = dir ? (SS - 1 - step) : step;
    const char* zxp = (const char*)(zx2 + ((size_t)(t*BB + eb)*128 + colq)*16);
    u32x4 ZA, ZB;
    #define LDZ() do { \
      asm volatile("global_load_dwordx4 %0, %1, off sc0 sc1" : "=v"(ZA) : "v"(zxp) : "memory"); \
      asm volatile("global_load_dwordx4 %0, %1, off offset:16 sc0 sc1" : "=v"(ZB) : "v"(zxp) : "memory"); \
    } while(0)
    #define ZOK (ok16(ZA[0]) && ok16(ZA[1]) && ok16(ZA[2]) && ok16(ZA[3]) \
              && ok16(ZB[0]) && ok16(ZB[1]) && ok16(ZB[2]) && ok16(ZB[3]))
    f32x4 a00 = {0.f,0.f,0.f,0.f}, a01 = {0.f,0.f,0.f,0.f};
    f32x4 a10 = {0.f,0.f,0.f,0.f}, a11 = {0.f,0.f,0.f,0.f};
    if (step > 0) {
      int tp = dir ? t + 1 : t - 1;
      const char* gsrc = (const char*)(hbuf + (size_t)tp*BB*HH) + goff;
      u32x4 S0, S1, S2, S3, S4, S5, S6, S7;
      #define LDC(r, off) asm volatile("global_load_dwordx4 %0, %1, off " off " sc0 sc1" \
                                       : "=v"(r) : "v"(gsrc) : "memory")
      for (;;) {
        LDZ();
        LDC(S0, "");            LDC(S1, "offset:128");
        LDC(S2, "offset:256");  LDC(S3, "offset:384");
        LDC(S4, "offset:512");  LDC(S5, "offset:640");
        LDC(S6, "offset:768");  LDC(S7, "offset:896");
        asm volatile("s_waitcnt vmcnt(0)" ::: "memory");
        __builtin_amdgcn_sched_barrier(0);  // rule #18
        bool ok = ZOK
               && S0[0]!=SENT && S0[1]!=SENT && S0[2]!=SENT && S0[3]!=SENT
               && S1[0]!=SENT && S1[1]!=SENT && S1[2]!=SENT && S1[3]!=SENT
               && S2[0]!=SENT && S2[1]!=SENT && S2[2]!=SENT && S2[3]!=SENT
               && S3[0]!=SENT && S3[1]!=SENT && S3[2]!=SENT && S3[3]!=SENT
               && S4[0]!=SENT && S4[1]!=SENT && S4[2]!=SENT && S4[3]!=SENT
               && S5[0]!=SENT && S5[1]!=SENT && S5[2]!=SENT && S5[3]!=SENT
               && S6[0]!=SENT && S6[1]!=SENT && S6[2]!=SENT && S6[3]!=SENT
               && S7[0]!=SENT && S7[1]!=SENT && S7[2]!=SENT && S7[3]!=SENT;
        if (__all(ok)) break;
        __builtin_amdgcn_s_sleep(1);
      }
      #undef LDC
      __builtin_amdgcn_sched_barrier(0);
      *(u32x4*)(swrite)       = S0;
      *(u32x4*)(swrite + 128) = S1;
      *(u32x4*)(swrite + 256) = S2;
      *(u32x4*)(swrite + 384) = S3;
      *(u32x4*)(swrite + 512) = S4;
      *(u32x4*)(swrite + 640) = S5;
      *(u32x4*)(swrite + 768) = S6;
      *(u32x4*)(swrite + 896) = S7;
      __syncthreads();   // B2: stage visible
      #pragma unroll
      for (int kf = 0; kf < 16; ++kf) {
        bf16x8 f0 = *(const bf16x8*)(sread0 + kf*64);
        bf16x8 f1 = *(const bf16x8*)(sread1 + kf*64);
        a00 = MFMA(f0, rb0[kf], a00);
        a01 = MFMA(f0, rb1[kf], a01);
        a10 = MFMA(f1, rb0[kf], a10);
        a11 = MFMA(f1, rb1[kf], a11);
      }
    } else {
      for (;;) {
        LDZ();
        asm volatile("s_waitcnt vmcnt(0)" ::: "memory");
        __builtin_amdgcn_sched_barrier(0);
        if (__all(ZOK)) break;
        __builtin_amdgcn_s_sleep(1);
      }
      __builtin_amdgcn_sched_barrier(0);
    }
    #undef LDZ
    #undef ZOK
    int zc = l & 15;
    int zr = (l >> 4) * 4;
    #pragma unroll
    for (int r = 0; r < 4; ++r) {
      zbuf[g][zc][zr + r]           = a00[r];
      zbuf[g][16 + zc][zr + r]      = a01[r];
      zbuf[g][zc][16 + zr + r]      = a10[r];
      zbuf[g][16 + zc][16 + zr + r] = a11[r];
    }
    __syncthreads();   // B3: gates exchanged
    int ecb = q * 4;
    float z0[4], z1[4], z2[4], z3[4];
    #pragma unroll
    for (int j = 0; j < 4; ++j) {
      z0[j] = zbuf[0][ecb + j][eb];
      z1[j] = zbuf[1][ecb + j][eb];
      z2[j] = zbuf[2][ecb + j][eb];
      z3[j] = zbuf[3][ecb + j][eb];
    }
    z0[0] += bf2f((u16)(ZA[0] & 0xffffu)); z0[1] += bf2f((u16)(ZA[0] >> 16));
    z0[2] += bf2f((u16)(ZA[1] & 0xffffu)); z0[3] += bf2f((u16)(ZA[1] >> 16));
    z1[0] += bf2f((u16)(ZA[2] & 0xffffu)); z1[1] += bf2f((u16)(ZA[2] >> 16));
    z1[2] += bf2f((u16)(ZA[3] & 0xffffu)); z1[3] += bf2f((u16)(ZA[3] >> 16));
    z2[0] += bf2f((u16)(ZB[0] & 0xffffu)); z2[1] += bf2f((u16)(ZB[0] >> 16));
    z2[2] += bf2f((u16)(ZB[1] & 0xffffu)); z2[3] += bf2f((u16)(ZB[1] >> 16));
    z3[0] += bf2f((u16)(ZB[2] & 0xffffu)); z3[1] += bf2f((u16)(ZB[2] >> 16));
    z3[2] += bf2f((u16)(ZB[3] & 0xffffu)); z3[3] += bf2f((u16)(ZB[3] >> 16));
    c0 = sigm(z1[0])*c0 + sigm(z0[0])*tanh_f(z2[0]);
    c1 = sigm(z1[1])*c1 + sigm(z0[1])*tanh_f(z2[1]);
    c2 = sigm(z1[2])*c2 + sigm(z0[2])*tanh_f(z2[2]);
    c3 = sigm(z1[3])*c3 + sigm(z0[3])*tanh_f(z2[3]);
    float h0 = sigm(z3[0])*tanh_f(c0);
    float h1 = sigm(z3[1])*tanh_f(c1);
    float h2 = sigm(z3[2])*tanh_f(c2);
    float h3 = sigm(z3[3])*tanh_f(c3);
    u32x2 hpk;
    hpk[0] = (u32)f2bf(h0) | ((u32)f2bf(h1) << 16);
    hpk[1] = (u32)f2bf(h2) | ((u32)f2bf(h3) << 16);
    u16* hp = hbuf + ((size_t)t*BB + eb)*HH + wgi*32 + q*4;
    asm volatile("global_store_dwordx2 %0, %1, off sc0 sc1" :: "v"(hp), "v"(hpk) : "memory");
  }
}

// ---------- phase C: h1 = [hf|hb] @ w1 + b1 ----------
__global__ __launch_bounds__(256) void k_dense(
    const u16* __restrict__ hf, const u16* __restrict__ hb,
    const u16* __restrict__ w1p, const float* __restrict__ b1,
    u16* __restrict__ h1)
{
  int mt = blockIdx.x, nt = blockIdx.y;
  int w = threadIdx.x >> 6, l = threadIdx.x & 63;
  int m0 = mt*128 + w*32;
  int r0 = m0 + (l & 15);
  const u16* f0 = hf + (size_t)r0*HH + (l >> 4)*8;
  const u16* f1 = hf + (size_t)(r0+16)*HH + (l >> 4)*8;
  const u16* g0 = hb + (size_t)r0*HH + (l >> 4)*8;
  const u16* g1 = hb + (size_t)(r0+16)*HH + (l >> 4)*8;
  f32x4 acc[2][8];
  #pragma unroll
  for (int i = 0; i < 2; ++i)
    #pragma unroll
    for (int j = 0; j < 8; ++j) acc[i][j] = (f32x4){0.f,0.f,0.f,0.f};
  const u16* bbase = w1p + ((size_t)(nt*8)*32)*512 + (size_t)l*8;
  for (int kf = 0; kf < 32; ++kf) {
    const u16* s0 = (kf < 16) ? (f0 + kf*32) : (g0 + (kf-16)*32);
    const u16* s1 = (kf < 16) ? (f1 + kf*32) : (g1 + (kf-16)*32);
    bf16x8 a0 = *(const bf16x8*)s0;
    bf16x8 a1 = *(const bf16x8*)s1;
    #pragma unroll
    for (int nf = 0; nf < 8; ++nf) {
      bf16x8 bv = *(const bf16x8*)(bbase + (size_t)(nf*32 + kf)*512);
      acc[0][nf] = MFMA(a0, bv, acc[0][nf]);
      acc[1][nf] = MFMA(a1, bv, acc[1][nf]);
    }
  }
  int cb = nt*128 + (l & 15);
  #pragma unroll
  for (int mi = 0; mi < 2; ++mi) {
    #pragma unroll
    for (int r = 0; r < 4; ++r) {
      int row = m0 + mi*16 + (l >> 4)*4 + r;
      #pragma unroll
      for (int nf = 0; nf < 8; ++nf) {
        int col = cb + nf*16;
        h1[(size_t)row*HH + col] = f2bf(acc[mi][nf][r] + b1[col]);
      }
    }
  }
}

// ---------- phase D: logits, softmax, probs, per-block NLL partials ----------
__global__ __launch_bounds__(256) void k_out(
    const u16* __restrict__ h1, const float* __restrict__ w2, const float* __restrict__ b2,
    const int* __restrict__ labels, float* __restrict__ out, float* __restrict__ part)
{
  int w = threadIdx.x >> 6, l = threadIdx.x & 63;
  float w2r[8][3];
  #pragma unroll
  for (int i = 0; i < 8; ++i)
    #pragma unroll
    for (int c = 0; c < 3; ++c) w2r[i][c] = w2[(l*8 + i)*3 + c];
  float b20 = b2[0], b21 = b2[1], b22 = b2[2];
  float nll = 0.f;
  int base = (blockIdx.x*4 + w)*16;
  for (int r = 0; r < 16; ++r) {
    int row = base + r;
    bf16x8 hv = *(const bf16x8*)(h1 + (size_t)row*HH + l*8);
    float s0 = 0.f, s1 = 0.f, s2 = 0.f;
    #pragma unroll
    for (int i = 0; i < 8; ++i) {
      float x = bf2f((u16)hv[i]);
      s0 += x*w2r[i][0]; s1 += x*w2r[i][1]; s2 += x*w2r[i][2];
    }
    #pragma unroll
    for (int off = 32; off > 0; off >>= 1) {
      s0 += __shfl_down(s0, off);
      s1 += __shfl_down(s1, off);
      s2 += __shfl_down(s2, off);
    }
    if (l == 0) {
      float l0 = s0+b20, l1 = s1+b21, l2 = s2+b22;
      float m = fmaxf(l0, fmaxf(l1, l2));
      float e0 = __expf(l0-m), e1 = __expf(l1-m), e2 = __expf(l2-m);
      float Z = e0+e1+e2, inv = 1.f/Z;
      int b = row & 31, s = row >> 5;
      float* po = out + ((size_t)b*SS + s)*3;
      po[0] = e0*inv; po[1] = e1*inv; po[2] = e2*inv;
      int lab = labels[b*SS + s];
      float ll = (lab == 0) ? l0 : (lab == 1 ? l1 : l2);
      nll += (m + __logf(Z)) - ll;
    }
  }
  __shared__ float ps[4];
  if (l == 0) ps[w] = nll;
  __syncthreads();
  if (threadIdx.x == 0) part[blockIdx.x] = ps[0]+ps[1]+ps[2]+ps[3];
}

__global__ void k_loss(const float* __restrict__ part, float* __restrict__ out) {
  __shared__ float sh[256];
  sh[threadIdx.x] = part[threadIdx.x];
  __syncthreads();
  for (int s = 128; s > 0; s >>= 1) {
    if (threadIdx.x < s) sh[threadIdx.x] += sh[threadIdx.x + s];
    __syncthreads();
  }
  if (threadIdx.x == 0) out[(size_t)MM*NC] = sh[0] / (float)BB;
}

extern "C" void kernel_launch(void* const* d_in, const int* in_sizes, int n_in,
                              void* d_out, int out_size, void* d_ws, size_t ws_size,
                              hipStream_t stream) {
  (void)in_sizes; (void)n_in; (void)out_size;
  const float* emb = (const float*)d_in[0];
  const float* fK  = (const float*)d_in[1];
  const float* fR  = (const float*)d_in[2];
  const float* fb  = (const float*)d_in[3];
  const float* bK  = (const float*)d_in[4];
  const float* bR  = (const float*)d_in[5];
  const float* bb  = (const float*)d_in[6];
  const float* w1  = (const float*)d_in[7];
  const float* b1  = (const float*)d_in[8];
  const float* w2  = (const float*)d_in[9];
  const float* b2  = (const float*)d_in[10];
  const int* ids   = (const int*)d_in[11];
  const int* prior = (const int*)d_in[12];
  const int* labels= (const int*)d_in[13];

  size_t off = 0;
  auto take = [&](size_t bytes) -> char* {
    char* p = (char*)d_ws + off;
    off += (bytes + 255) & ~(size_t)255;
    return p;
  };
  u16* embT = (u16*)take((size_t)VV*EE*2);
  u16* Kfp  = (u16*)take((size_t)EE*G4*2);
  u16* Kbp  = (u16*)take((size_t)EE*G4*2);
  u16* Rfp  = (u16*)take((size_t)HH*G4*2);
  u16* Rbp  = (u16*)take((size_t)HH*G4*2);
  u16* w1p  = (u16*)take((size_t)(2*HH)*HH*2);
  u16* zxf  = (u16*)take((size_t)MM*G4*2);
  u16* zxb  = (u16*)take((size_t)MM*G4*2);
  u16* hf   = (u16*)take((size_t)MM*HH*2);
  u16* hb   = (u16*)take((size_t)MM*HH*2);
  u16* h1   = (u16*)take((size_t)MM*HH*2);
  float* part = (float*)take(256*4);
  if (off > ws_size) return;

  // sentinel-fill zx and h buffers (every launch: replays must re-arm the sync)
  hipMemsetAsync(zxf, 0xFF, (size_t)MM*G4*2, stream);
  hipMemsetAsync(zxb, 0xFF, (size_t)MM*G4*2, stream);
  hipMemsetAsync(hf, 0xFF, (size_t)MM*HH*2, stream);
  hipMemsetAsync(hb, 0xFF, (size_t)MM*HH*2, stream);
  k_prep<<<14816, 256, 0, stream>>>(emb, embT, fK, Kfp, bK, Kbp, fR, Rfp, bR, Rbp, w1, w1p);
  k_fused<<<256, 256, 0, stream>>>(embT, Kfp, Kbp, fb, bb, fK, bK, ids, prior,
                                   zxf, zxb, Rfp, Rbp, hf, hb);
  k_dense<<<dim3(128,4), 256, 0, stream>>>(hf, hb, w1p, b1, h1);
  k_out<<<256, 256, 0, stream>>>(h1, w2, b2, labels, (float*)d_out, part);
  k_loss<<<1, 256, 0, stream>>>(part, (float*)d_out);
}

// Round 13
// 2217.610 us; speedup vs baseline: 1.0148x; 1.0148x over previous
//
#include <hip/hip_runtime.h>
#include <hip/hip_bf16.h>

#define BB 32
#define SS 512
#define HH 512
#define VV 32000
#define EE 768
#define NC 3
#define G4 2048
#define MM (BB*SS)
#define SENT 0xFFFFFFFFu

typedef __attribute__((ext_vector_type(8))) short bf16x8;
typedef __attribute__((ext_vector_type(4))) float f32x4;
typedef unsigned int u32;
typedef unsigned short u16;
typedef __attribute__((ext_vector_type(4))) u32 u32x4;
typedef __attribute__((ext_vector_type(2))) u32 u32x2;

#define MFMA(a,b,c) __builtin_amdgcn_mfma_f32_16x16x32_bf16(a,b,c,0,0,0)

static __device__ __forceinline__ u16 f2bf(float f) {
  union { float f; u32 u; } v; v.f = f;
  return (u16)((v.u + 0x7fffu + ((v.u >> 16) & 1u)) >> 16);
}
static __device__ __forceinline__ float bf2f(u16 h) {
  union { u32 u; float f; } v; v.u = ((u32)h) << 16;
  return v.f;
}
static __device__ __forceinline__ float sigm(float x) { return 1.f/(1.f+__expf(-x)); }
static __device__ __forceinline__ float tanh_f(float x) {
  x = fminf(8.f, fmaxf(-8.f, x));
  float t = __expf(2.f*x);
  return (t-1.f)/(t+1.f);
}
static __device__ __forceinline__ bool ok16(u32 v) {
  return ((v & 0xFFFFu) != 0xFFFFu) && ((v >> 16) != 0xFFFFu);
}

// ---------- merged prep: conv + 4 packs + W-collapse (w1@w2, b1@w2+b2) ----------
static __device__ void conv_body(int blk, const float* __restrict__ src, u16* __restrict__ dst) {
  int i = blk * 256 + threadIdx.x;
  if (i >= VV*EE/8) return;
  const float4* s = ((const float4*)src) + (size_t)i*2;
  float4 a = s[0], b = s[1];
  u32 x = (u32)f2bf(a.x) | ((u32)f2bf(a.y) << 16);
  u32 y = (u32)f2bf(a.z) | ((u32)f2bf(a.w) << 16);
  u32 z = (u32)f2bf(b.x) | ((u32)f2bf(b.y) << 16);
  u32 w = (u32)f2bf(b.z) | ((u32)f2bf(b.w) << 16);
  ((uint4*)dst)[i] = make_uint4(x, y, z, w);
}
static __device__ void pack_body(int blk, const float* __restrict__ src, u16* __restrict__ dst, int K, int N) {
  int tid = blk * 256 + threadIdx.x;
  int nkf = K >> 5;
  int l = tid & 63, fi = tid >> 6;
  int kf = fi % nkf, nf = fi / nkf;
  if (nf >= (N >> 4)) return;
  int col = nf * 16 + (l & 15);
  int k0 = kf * 32 + (l >> 4) * 8;
  u32 o[4];
  #pragma unroll
  for (int j = 0; j < 4; ++j) {
    u16 lo = f2bf(src[(size_t)(k0 + 2*j) * N + col]);
    u16 hi = f2bf(src[(size_t)(k0 + 2*j + 1) * N + col]);
    o[j] = (u32)lo | ((u32)hi << 16);
  }
  *((uint4*)(dst + (size_t)tid * 8)) = make_uint4(o[0], o[1], o[2], o[3]);
}
static __device__ void collapse_body(int blk, const float* __restrict__ w1,
    const float* __restrict__ w2, const float* __restrict__ b1, const float* __restrict__ b2,
    float* __restrict__ Wc, float* __restrict__ Wb) {
  int g = blk * 256 + threadIdx.x;
  if (g < 3072) {
    int r = g / 3, c = g % 3;
    float acc = 0.f;
    for (int k = 0; k < HH; ++k) acc += w1[(size_t)r*HH + k] * w2[k*3 + c];
    Wc[g] = acc;
  } else if (g < 3075) {
    int c = g - 3072;
    float acc = b2[c];
    for (int k = 0; k < HH; ++k) acc += b1[k] * w2[k*3 + c];
    Wb[c] = acc;
  }
}
__global__ __launch_bounds__(256) void k_prep(
    const float* emb, u16* embT,
    const float* fK, u16* Kfp, const float* bK, u16* Kbp,
    const float* fR, u16* Rfp, const float* bR, u16* Rbp,
    const float* w1, const float* w2, const float* b1, const float* b2,
    float* Wc, float* Wb)
{
  int b = blockIdx.x;
  if      (b < 12000) conv_body(b, emb, embT);
  else if (b < 12768) pack_body(b-12000, fK, Kfp, EE, G4);
  else if (b < 13536) pack_body(b-12768, bK, Kbp, EE, G4);
  else if (b < 14048) pack_body(b-13536, fR, Rfp, HH, G4);
  else if (b < 14560) pack_body(b-14048, bR, Rbp, HH, G4);
  else                collapse_body(b-14560, w1, w2, b1, b2, Wc, Wb);
}

// ---------- proj role: zx2 = gather(emb) @ K + bias + K_prior_row ----------
static __device__ __forceinline__ void proj_role(
    int pid, char* smem,
    const u16* __restrict__ embT, const u16* __restrict__ Kfp, const u16* __restrict__ Kbp,
    const float* __restrict__ fb_, const float* __restrict__ bb_,
    const float* __restrict__ fK_, const float* __restrict__ bK_,
    const int* __restrict__ ids, const int* __restrict__ prior,
    u16* __restrict__ zx2f, u16* __restrict__ zx2b)
{
  int w = threadIdx.x >> 6, l = threadIdx.x & 63;
  int dir = pid >= 112;
  int i0 = dir ? pid - 112 : pid;
  const u16* Bp = dir ? Kbp : Kfp;
  const float* bias = dir ? bb_ : fb_;
  const float* Kp = (dir ? bK_ : fK_) + (size_t)EE * G4;
  u16* zx2 = dir ? zx2b : zx2f;
  u16* lt = (u16*)smem;                 // [128][136] u16 = 34816B
  for (int i = i0; i < 2048; i += 112) {
    int mtseq = i >> 4, nt = i & 15;
    int mt = dir ? (127 - mtseq) : mtseq;
    int m0 = mt * 128 + w * 32;
    int r0 = m0 + (l & 15);
    int id0 = ids[(r0 & 31) * SS + (r0 >> 5)];
    int id1 = ids[((r0 + 16) & 31) * SS + ((r0 + 16) >> 5)];
    const u16* a0p = embT + (size_t)id0 * EE + (l >> 4) * 8;
    const u16* a1p = embT + (size_t)id1 * EE + (l >> 4) * 8;
    f32x4 acc[2][8];
    #pragma unroll
    for (int a = 0; a < 2; ++a)
      #pragma unroll
      for (int j = 0; j < 8; ++j) acc[a][j] = (f32x4){0.f,0.f,0.f,0.f};
    const u16* bbase = Bp + ((size_t)(nt*8)*24)*512 + (size_t)l*8;
    for (int kf = 0; kf < 24; ++kf) {
      bf16x8 a0 = *(const bf16x8*)(a0p + kf*32);
      bf16x8 a1 = *(const bf16x8*)(a1p + kf*32);
      #pragma unroll
      for (int nf = 0; nf < 8; ++nf) {
        bf16x8 bv = *(const bf16x8*)(bbase + (size_t)(nf*24 + kf)*512);
        acc[0][nf] = MFMA(a0, bv, acc[0][nf]);
        acc[1][nf] = MFMA(a1, bv, acc[1][nf]);
      }
    }
    __syncthreads();   // guard: previous tile's readout done before overwrite
    #pragma unroll
    for (int mi = 0; mi < 2; ++mi) {
      #pragma unroll
      for (int r = 0; r < 4; ++r) {
        int rloc = w*32 + mi*16 + (l >> 4)*4 + r;
        int row = mt*128 + rloc;
        int p = prior[(row & 31) * SS + (row >> 5)];
        const float* kr = Kp + (size_t)p * G4;
        #pragma unroll
        for (int nf = 0; nf < 8; ++nf) {
          int lc = (l & 15) + nf*16;
          int colg = nt*128 + lc;
          lt[rloc*136 + lc] = f2bf(acc[mi][nf][r] + bias[colg] + kr[colg]);
        }
      }
    }
    __syncthreads();   // tile staged
    int g = nt >> 2, cqb = (nt & 3) * 32;
    int cql = threadIdx.x & 31;
    #pragma unroll
    for (int k = 0; k < 8; ++k) {
      int rloc = k*16 + (threadIdx.x >> 5);
      int s = mt*4 + (rloc >> 5);
      int b = rloc & 31;
      u32x2 v0 = *(const u32x2*)(lt + rloc*136 + cql*4);
      u32x2 v1 = *(const u32x2*)(lt + (rloc+8)*136 + cql*4);
      u16* d0 = zx2 + (((size_t)(s*BB + b)*128 + cqb + cql)*16 + g*4);
      int rloc1 = rloc + 8;
      int s1 = mt*4 + (rloc1 >> 5), b1 = rloc1 & 31;
      u16* d1 = zx2 + (((size_t)(s1*BB + b1)*128 + cqb + cql)*16 + g*4);
      asm volatile("global_store_dwordx2 %0, %1, off sc0 sc1" :: "v"(d0), "v"(v0) : "memory");
      asm volatile("global_store_dwordx2 %0, %1, off sc0 sc1" :: "v"(d1), "v"(v1) : "memory");
    }
  }
}

// ---------- out role: probs + NLL, h1 never materialized (w1@w2 collapsed) ----------
// 128 workers, one 4-timestep stripe each, center-outward order. Wave wv owns
// s = j*4+wv (32 batch rows). h rows sentinel-polled (sc0 sc1 data-poll).
static __device__ __forceinline__ void out_role(
    int p, char* smem, const float* __restrict__ Wc, const float* __restrict__ Wb,
    const u16* __restrict__ hf, const u16* __restrict__ hb,
    const int* __restrict__ labels, float* __restrict__ out, float* __restrict__ part)
{
  if (p >= 128) return;
  int k = p >> 1;
  int j = (p & 1) ? (64 + k) : (63 - k);
  __syncthreads();                       // proj done with smem
  float* Wl = (float*)smem;              // [1024*3] fp32 = 12288B
  for (int i = threadIdx.x; i < 3072; i += 256) Wl[i] = Wc[i];
  __syncthreads();
  float wb0 = Wb[0], wb1 = Wb[1], wb2 = Wb[2];
  int wv = threadIdx.x >> 6, l = threadIdx.x & 63;
  int s = j*4 + wv;
  float nll = 0.f;
  for (int b4 = 0; b4 < 32; b4 += 4) {
    const char* fbase = (const char*)(hf + ((size_t)s*BB + b4)*HH) + l*16;
    const char* gbase = (const char*)(hb + ((size_t)s*BB + b4)*HH) + l*16;
    union { u32x4 u; u16 h[8]; } F[4], G[4];
    for (;;) {
      #define LDH(r) do { \
        asm volatile("global_load_dwordx4 %0, %1, off offset:%2 sc0 sc1" \
                     : "=v"(F[r].u) : "v"(fbase), "i"(r*1024) : "memory"); \
        asm volatile("global_load_dwordx4 %0, %1, off offset:%2 sc0 sc1" \
                     : "=v"(G[r].u) : "v"(gbase), "i"(r*1024) : "memory"); \
      } while(0)
      LDH(0); LDH(1); LDH(2); LDH(3);
      #undef LDH
      asm volatile("s_waitcnt vmcnt(0)" ::: "memory");
      __builtin_amdgcn_sched_barrier(0);  // rule #18
      bool ok = true;
      #pragma unroll
      for (int r = 0; r < 4; ++r) {
        #pragma unroll
        for (int d = 0; d < 4; ++d)
          ok = ok && ok16(F[r].u[d]) && ok16(G[r].u[d]);
      }
      if (__all(ok)) break;
      __builtin_amdgcn_s_sleep(64);
    }
    __builtin_amdgcn_sched_barrier(0);
    #pragma unroll
    for (int r = 0; r < 4; ++r) {
      int b = b4 + r;
      float s0 = 0.f, s1 = 0.f, s2 = 0.f;
      #pragma unroll
      for (int i = 0; i < 8; ++i) {
        float xf = bf2f(F[r].h[i]);
        const float* wr = Wl + (l*8 + i)*3;
        s0 += xf*wr[0]; s1 += xf*wr[1]; s2 += xf*wr[2];
        float xg = bf2f(G[r].h[i]);
        const float* wr2 = Wl + (512 + l*8 + i)*3;
        s0 += xg*wr2[0]; s1 += xg*wr2[1]; s2 += xg*wr2[2];
      }
      #pragma unroll
      for (int off = 32; off > 0; off >>= 1) {
        s0 += __shfl_down(s0, off);
        s1 += __shfl_down(s1, off);
        s2 += __shfl_down(s2, off);
      }
      if (l == 0) {
        float l0 = s0+wb0, l1 = s1+wb1, l2 = s2+wb2;
        float m = fmaxf(l0, fmaxf(l1, l2));
        float e0 = __expf(l0-m), e1 = __expf(l1-m), e2 = __expf(l2-m);
        float Z = e0+e1+e2, inv = 1.f/Z;
        float* po = out + ((size_t)b*SS + s)*3;
        po[0] = e0*inv; po[1] = e1*inv; po[2] = e2*inv;
        int lab = labels[b*SS + s];
        float ll = (lab == 0) ? l0 : (lab == 1 ? l1 : l2);
        nll += (m + __logf(Z)) - ll;
      }
    }
  }
  if (l == 0) part[j*4 + wv] = nll;
}

// ---------- fused kernel: wg 0..31 = scan, wg 32..255 = proj -> out workers ----------
__global__ __launch_bounds__(256, 1) void k_fused(
    const u16* __restrict__ embT, const u16* __restrict__ Kfp, const u16* __restrict__ Kbp,
    const float* __restrict__ fb, const float* __restrict__ bb,
    const float* __restrict__ fK, const float* __restrict__ bK,
    const int* __restrict__ ids, const int* __restrict__ prior,
    u16* __restrict__ zx2f, u16* __restrict__ zx2b,
    const u16* __restrict__ Rf, const u16* __restrict__ Rb,
    u16* __restrict__ hf, u16* __restrict__ hb,
    const float* __restrict__ Wc, const float* __restrict__ Wb,
    const int* __restrict__ labels, float* __restrict__ out, float* __restrict__ part)
{
  __shared__ char smem[52224];
  char* hstage = smem;                                  // 32*1040 = 33280
  float (*zbuf)[32][33] = (float (*)[32][33])(smem + 33280);  // 16896
  char* hcoal = smem + 50176;                           // 2048

  int wg = blockIdx.x;
  if (wg >= 32) {
    proj_role(wg - 32, smem, embT, Kfp, Kbp, fb, bb, fK, bK, ids, prior, zx2f, zx2b);
    out_role(wg - 32, smem, Wc, Wb, hf, hb, labels, out, part);
    return;
  }
  int dir = wg >> 4, wgi = wg & 15;
  const u16* zx2 = dir ? zx2b : zx2f;
  const u16* Rp = dir ? Rb : Rf;
  u16* hbuf = dir ? hb : hf;
  int tid = threadIdx.x;
  int g = tid >> 6, l = tid & 63;
  int ncb0 = g*32 + wgi*2;
  bf16x8 rb0[16], rb1[16];
  #pragma unroll
  for (int kf = 0; kf < 16; ++kf) {
    rb0[kf] = *(const bf16x8*)(Rp + (((size_t)ncb0*16 + kf)*64 + l)*8);
    rb1[kf] = *(const bf16x8*)(Rp + (((size_t)(ncb0+1)*16 + kf)*64 + l)*8);
  }

  int eb = tid >> 3;            // batch 0..31
  int q = tid & 7;              // colq within wg
  int colq = wgi*8 + q;
  const char* sread0 = hstage + (l & 15)*1040 + (l >> 4)*16;
  const char* sread1 = sread0 + 16*1040;
  char* swrite = hstage + (tid >> 3)*1040 + q*16;
  size_t goff = (size_t)(tid >> 3)*1024 + q*16;

  float c0 = 0.f, c1 = 0.f, c2 = 0.f, c3 = 0.f;
  for (int step = 0; step < SS; ++step) {
    int t = dir ? (SS - 1 - step) : step;
    const char* zxp = (const char*)(zx2 + ((size_t)(t*BB + eb)*128 + colq)*16);
    u32x4 ZA, ZB;
    #define LDZ() do { \
      asm volatile("global_load_dwordx4 %0, %1, off sc0 sc1" : "=v"(ZA) : "v"(zxp) : "memory"); \
      asm volatile("global_load_dwordx4 %0, %1, off offset:16 sc0 sc1" : "=v"(ZB) : "v"(zxp) : "memory"); \
    } while(0)
    #define ZOK (ok16(ZA[0]) && ok16(ZA[1]) && ok16(ZA[2]) && ok16(ZA[3]) \
              && ok16(ZB[0]) && ok16(ZB[1]) && ok16(ZB[2]) && ok16(ZB[3]))
    f32x4 a00 = {0.f,0.f,0.f,0.f}, a01 = {0.f,0.f,0.f,0.f};
    f32x4 a10 = {0.f,0.f,0.f,0.f}, a11 = {0.f,0.f,0.f,0.f};
    if (step > 0) {
      int tp = dir ? t + 1 : t - 1;
      const char* gsrc = (const char*)(hbuf + (size_t)tp*BB*HH) + goff;
      u32x4 S0, S1, S2, S3, S4, S5, S6, S7;
      #define LDC(r, off) asm volatile("global_load_dwordx4 %0, %1, off " off " sc0 sc1" \
                                       : "=v"(r) : "v"(gsrc) : "memory")
      for (;;) {
        LDZ();
        LDC(S0, "");            LDC(S1, "offset:128");
        LDC(S2, "offset:256");  LDC(S3, "offset:384");
        LDC(S4, "offset:512");  LDC(S5, "offset:640");
        LDC(S6, "offset:768");  LDC(S7, "offset:896");
        asm volatile("s_waitcnt vmcnt(0)" ::: "memory");
        __builtin_amdgcn_sched_barrier(0);  // rule #18
        bool ok = ZOK
               && S0[0]!=SENT && S0[1]!=SENT && S0[2]!=SENT && S0[3]!=SENT
               && S1[0]!=SENT && S1[1]!=SENT && S1[2]!=SENT && S1[3]!=SENT
               && S2[0]!=SENT && S2[1]!=SENT && S2[2]!=SENT && S2[3]!=SENT
               && S3[0]!=SENT && S3[1]!=SENT && S3[2]!=SENT && S3[3]!=SENT
               && S4[0]!=SENT && S4[1]!=SENT && S4[2]!=SENT && S4[3]!=SENT
               && S5[0]!=SENT && S5[1]!=SENT && S5[2]!=SENT && S5[3]!=SENT
               && S6[0]!=SENT && S6[1]!=SENT && S6[2]!=SENT && S6[3]!=SENT
               && S7[0]!=SENT && S7[1]!=SENT && S7[2]!=SENT && S7[3]!=SENT;
        if (__all(ok)) break;
        __builtin_amdgcn_s_sleep(1);
      }
      #undef LDC
      __builtin_amdgcn_sched_barrier(0);
      *(u32x4*)(swrite)       = S0;
      *(u32x4*)(swrite + 128) = S1;
      *(u32x4*)(swrite + 256) = S2;
      *(u32x4*)(swrite + 384) = S3;
      *(u32x4*)(swrite + 512) = S4;
      *(u32x4*)(swrite + 640) = S5;
      *(u32x4*)(swrite + 768) = S6;
      *(u32x4*)(swrite + 896) = S7;
      __syncthreads();   // B2: stage visible
      #pragma unroll
      for (int kf = 0; kf < 16; ++kf) {
        bf16x8 f0 = *(const bf16x8*)(sread0 + kf*64);
        bf16x8 f1 = *(const bf16x8*)(sread1 + kf*64);
        a00 = MFMA(f0, rb0[kf], a00);
        a01 = MFMA(f0, rb1[kf], a01);
        a10 = MFMA(f1, rb0[kf], a10);
        a11 = MFMA(f1, rb1[kf], a11);
      }
    } else {
      for (;;) {
        LDZ();
        asm volatile("s_waitcnt vmcnt(0)" ::: "memory");
        __builtin_amdgcn_sched_barrier(0);
        if (__all(ZOK)) break;
        __builtin_amdgcn_s_sleep(1);
      }
      __builtin_amdgcn_sched_barrier(0);
    }
    #undef LDZ
    #undef ZOK
    int zc = l & 15;
    int zr = (l >> 4) * 4;
    #pragma unroll
    for (int r = 0; r < 4; ++r) {
      zbuf[g][zc][zr + r]           = a00[r];
      zbuf[g][16 + zc][zr + r]      = a01[r];
      zbuf[g][zc][16 + zr + r]      = a10[r];
      zbuf[g][16 + zc][16 + zr + r] = a11[r];
    }
    __syncthreads();   // B3: gates exchanged
    int ecb = q * 4;
    float z0[4], z1[4], z2[4], z3[4];
    #pragma unroll
    for (int jx = 0; jx < 4; ++jx) {
      z0[jx] = zbuf[0][ecb + jx][eb];
      z1[jx] = zbuf[1][ecb + jx][eb];
      z2[jx] = zbuf[2][ecb + jx][eb];
      z3[jx] = zbuf[3][ecb + jx][eb];
    }
    z0[0] += bf2f((u16)(ZA[0] & 0xffffu)); z0[1] += bf2f((u16)(ZA[0] >> 16));
    z0[2] += bf2f((u16)(ZA[1] & 0xffffu)); z0[3] += bf2f((u16)(ZA[1] >> 16));
    z1[0] += bf2f((u16)(ZA[2] & 0xffffu)); z1[1] += bf2f((u16)(ZA[2] >> 16));
    z1[2] += bf2f((u16)(ZA[3] & 0xffffu)); z1[3] += bf2f((u16)(ZA[3] >> 16));
    z2[0] += bf2f((u16)(ZB[0] & 0xffffu)); z2[1] += bf2f((u16)(ZB[0] >> 16));
    z2[2] += bf2f((u16)(ZB[1] & 0xffffu)); z2[3] += bf2f((u16)(ZB[1] >> 16));
    z3[0] += bf2f((u16)(ZB[2] & 0xffffu)); z3[1] += bf2f((u16)(ZB[2] >> 16));
    z3[2] += bf2f((u16)(ZB[3] & 0xffffu)); z3[3] += bf2f((u16)(ZB[3] >> 16));
    c0 = sigm(z1[0])*c0 + sigm(z0[0])*tanh_f(z2[0]);
    c1 = sigm(z1[1])*c1 + sigm(z0[1])*tanh_f(z2[1]);
    c2 = sigm(z1[2])*c2 + sigm(z0[2])*tanh_f(z2[2]);
    c3 = sigm(z1[3])*c3 + sigm(z0[3])*tanh_f(z2[3]);
    float h0 = sigm(z3[0])*tanh_f(c0);
    float h1 = sigm(z3[1])*tanh_f(c1);
    float h2 = sigm(z3[2])*tanh_f(c2);
    float h3 = sigm(z3[3])*tanh_f(c3);
    u32x2 hpk;
    hpk[0] = (u32)f2bf(h0) | ((u32)f2bf(h1) << 16);
    hpk[1] = (u32)f2bf(h2) | ((u32)f2bf(h3) << 16);
    // coalesced h-store: gather wg's 2KB slab in LDS, then 128 lanes store
    // 16B each (full 64B sectors at MALL -> no partial-write RMW merges)
    *(u32x2*)(hcoal + eb*64 + q*8) = hpk;
    __syncthreads();   // B4: slab assembled
    if (tid < 128) {
      int b = tid >> 2, ch = tid & 3;
      u32x4 v = *(const u32x4*)(hcoal + b*64 + ch*16);
      char* hp = (char*)(hbuf + ((size_t)t*BB + b)*HH + wgi*32) + ch*16;
      asm volatile("global_store_dwordx4 %0, %1, off sc0 sc1" :: "v"(hp), "v"(v) : "memory");
    }
    // producer never waits: RAW-only dependency, consumers validate data
  }
}

__global__ void k_loss(const float* __restrict__ part, float* __restrict__ out) {
  __shared__ float sh[256];
  sh[threadIdx.x] = part[threadIdx.x] + part[threadIdx.x + 256];
  __syncthreads();
  for (int s = 128; s > 0; s >>= 1) {
    if (threadIdx.x < s) sh[threadIdx.x] += sh[threadIdx.x + s];
    __syncthreads();
  }
  if (threadIdx.x == 0) out[(size_t)MM*NC] = sh[0] / (float)BB;
}

extern "C" void kernel_launch(void* const* d_in, const int* in_sizes, int n_in,
                              void* d_out, int out_size, void* d_ws, size_t ws_size,
                              hipStream_t stream) {
  (void)in_sizes; (void)n_in; (void)out_size;
  const float* emb = (const float*)d_in[0];
  const float* fK  = (const float*)d_in[1];
  const float* fR  = (const float*)d_in[2];
  const float* fb  = (const float*)d_in[3];
  const float* bK  = (const float*)d_in[4];
  const float* bR  = (const float*)d_in[5];
  const float* bb  = (const float*)d_in[6];
  const float* w1  = (const float*)d_in[7];
  const float* b1  = (const float*)d_in[8];
  const float* w2  = (const float*)d_in[9];
  const float* b2  = (const float*)d_in[10];
  const int* ids   = (const int*)d_in[11];
  const int* prior = (const int*)d_in[12];
  const int* labels= (const int*)d_in[13];

  size_t off = 0;
  auto take = [&](size_t bytes) -> char* {
    char* p = (char*)d_ws + off;
    off += (bytes + 255) & ~(size_t)255;
    return p;
  };
  u16* embT = (u16*)take((size_t)VV*EE*2);
  u16* Kfp  = (u16*)take((size_t)EE*G4*2);
  u16* Kbp  = (u16*)take((size_t)EE*G4*2);
  u16* Rfp  = (u16*)take((size_t)HH*G4*2);
  u16* Rbp  = (u16*)take((size_t)HH*G4*2);
  u16* zxf  = (u16*)take((size_t)MM*G4*2);
  u16* zxb  = (u16*)take((size_t)MM*G4*2);
  u16* hf   = (u16*)take((size_t)MM*HH*2);
  u16* hb   = (u16*)take((size_t)MM*HH*2);
  float* Wc = (float*)take(3072*4);
  float* Wb = (float*)take(16);
  float* part = (float*)take(512*4);
  if (off > ws_size) return;

  // sentinel-fill zx and h buffers (every launch: replays must re-arm the sync)
  hipMemsetAsync(zxf, 0xFF, (size_t)MM*G4*2, stream);
  hipMemsetAsync(zxb, 0xFF, (size_t)MM*G4*2, stream);
  hipMemsetAsync(hf, 0xFF, (size_t)MM*HH*2, stream);
  hipMemsetAsync(hb, 0xFF, (size_t)MM*HH*2, stream);
  k_prep<<<14573, 256, 0, stream>>>(emb, embT, fK, Kfp, bK, Kbp, fR, Rfp, bR, Rbp,
                                    w1, w2, b1, b2, Wc, Wb);
  k_fused<<<256, 256, 0, stream>>>(embT, Kfp, Kbp, fb, bb, fK, bK, ids, prior,
                                   zxf, zxb, Rfp, Rbp, hf, hb,
                                   Wc, Wb, labels, (float*)d_out, part);
  k_loss<<<1, 256, 0, stream>>>(part, (float*)d_out);
}